// Round 1
// 102.608 us; speedup vs baseline: 1.0261x; 1.0261x over previous
//
#include <hip/hip_runtime.h>
#include <math.h>

// B=4, C=64, H=W=128, O=64, K=3, pad=1, stride=1
// Round-14: R13 (green, 105.3us) + ONE delta: phase-2 bilinear convert done in
// packed-f32 pairs (v_pk_mul/fma_f32 via <2 x float>, v_cvt_pk_bf16_f32 via asm).
// Cuts convert sequence ~23 -> ~13 VALU insts per bf16-pair (~40% of dominant
// phase-2 VALU stream). Geometry, staging, MFMA layout verbatim from R13.
// Known harness floor ~52us (268MB ws re-poison fill @ ~6TB/s + restores) is inside dur_us.
// ws: xb 8.39 MB + wtF + pgwF (~8.5 MB)

typedef __attribute__((ext_vector_type(8))) short short8;   // 8 bf16 (A/B frag)
typedef __attribute__((ext_vector_type(4))) float f32x4;    // C/D frag
typedef __attribute__((ext_vector_type(2))) float f32x2;    // packed-f32 pair

__device__ __forceinline__ float b2f(unsigned short h) {
    union { unsigned u; float f; } v; v.u = ((unsigned)h) << 16; return v.f;
}
__device__ __forceinline__ unsigned short f2b(float f) {   // RNE
    union { float f; unsigned u; } v; v.f = f;
    unsigned r = v.u + 0x7FFFu + ((v.u >> 16) & 1u);
    return (unsigned short)(r >> 16);
}

// unpack a u32 holding 2 bf16 (lo=elem 2p, hi=elem 2p+1) into exact f32 pair
__device__ __forceinline__ f32x2 unpk_bf16(unsigned u) {
    union { unsigned u; float f; } lo, hi;
    lo.u = u << 16; hi.u = u & 0xFFFF0000u;
    return (f32x2){lo.f, hi.f};
}
// pack 2 f32 -> 2 bf16 (RNE) in one instruction
__device__ __forceinline__ unsigned cvt_pk_bf16(f32x2 v) {
    float lo = v.x, hi = v.y; unsigned d;
    asm("v_cvt_pk_bf16_f32 %0, %1, %2" : "=v"(d) : "v"(lo), "v"(hi));
    return d;
}
__device__ __forceinline__ unsigned uget(const uint4& v, int p) {
    return p == 0 ? v.x : p == 1 ? v.y : p == 2 ? v.z : v.w;
}

// ---------------- K0: NCHW fp32 -> NHWC bf16 (exact R12) ----------------
__global__ __launch_bounds__(256) void k_nhwc(const float* __restrict__ x,
                                              unsigned short* __restrict__ xb) {
    __shared__ float tile[64][33];
    int bid = blockIdx.x;
    int b = bid >> 9, h = (bid >> 2) & 127, w0 = (bid & 3) * 32;
    int t = threadIdx.x;
    for (int idx = t; idx < 2048; idx += 256) {
        int c = idx >> 5, w = idx & 31;
        tile[c][w] = x[((b * 64 + c) * 128 + h) * 128 + w0 + w];
    }
    __syncthreads();
    {
        int wl = t >> 3, c0 = (t & 7) * 8;
        short8 v;
#pragma unroll
        for (int e = 0; e < 8; ++e) v[e] = (short)f2b(tile[c0 + e][wl]);
        *(short8*)&xb[(((size_t)b * 128 + h) * 128 + w0 + wl) * 64 + c0] = v;
    }
}

// ---------------- K1: pack weights to bf16, FRAGMENT order (exact R12) ----------------
__global__ __launch_bounds__(256) void k_pack_w(const float* __restrict__ weight,
                                                const float* __restrict__ pg_w,
                                                unsigned short* __restrict__ wtF,
                                                unsigned short* __restrict__ pgwF) {
    int idx = blockIdx.x * 256 + threadIdx.x;
    if (idx < 36864) {
        int e = idx & 7, l = (idx >> 3) & 63, grp = idx >> 9;   // grp 0..71
        int nt = grp & 3, kb = (grp >> 2) & 1, kk = grp >> 3;
        int ln = l & 15, quad = l >> 4;
        int o = nt * 16 + ln;
        int c = kb * 32 + quad * 8 + e;
        wtF[idx] = f2b(weight[(o * 64 + c) * 9 + kk]);
    }
    int i2 = idx - 36864;
    if (i2 >= 0 && i2 < 18432) {
        int e = i2 & 7, l = (i2 >> 3) & 63, grp = i2 >> 9;      // grp 0..35
        int tile = grp & 1, kb = grp >> 1;
        int ln = l & 15, quad = l >> 4;
        int p = tile * 16 + ln;
        int k = kb * 32 + quad * 8 + e;
        float v = 0.f;
        if (p < 27) {
            int q = k >> 6, c = k & 63;
            v = pg_w[(p * 64 + c) * 9 + q];
        }
        pgwF[i2] = f2b(v);
    }
}

// ---------------- K2: fused offset-conv + deformable conv, 8x16 tile ----------------
// 512 blocks (b x 16 x 8), tile = 8 rows x 16 cols. 512 threads = 8 waves; wave w = row w.
__global__ __launch_bounds__(512) void k_fused(const unsigned short* __restrict__ xb,
                                               const unsigned short* __restrict__ pgwF,
                                               const float* __restrict__ pg_b,
                                               const unsigned short* __restrict__ wtF,
                                               const float* __restrict__ bias,
                                               float* __restrict__ out) {
    __shared__ unsigned short patch[260 * 64];   // 33.3 KB [pos=yy*20+xx][c ^ (pos&7)*8]
    __shared__ float P_s[27 * 129];              // 13.9 KB [param][px], stride 129

    int bid = blockIdx.x;
    int b  = bid >> 7;
    int h0 = ((bid >> 3) & 15) * 8;
    int w0 = (bid & 7) * 16;
    int t = threadIdx.x;
    int base_y = h0 - 2, base_x = w0 - 2;
    const unsigned short* xbb = xb + (size_t)b * 16384 * 64;

    // ---- phase 0: stage patch from xb; 2080 b128 chunks, coalesced ----
    for (int i = t; i < 2080; i += 512) {
        int yy = i / 160;                 // 8 chunks per 20-col row
        int r  = i - yy * 160;
        int xx = r >> 3;
        int c0 = (r & 7) * 8;
        int gy = base_y + yy, gx = base_x + xx;
        int pos = yy * 20 + xx;
        short8 v = (short8)0;
        if (((unsigned)gy < 128u) && ((unsigned)gx < 128u))
            v = *(const short8*)&xbb[(gy * 128 + gx) * 64 + c0];
        *(short8*)&patch[pos * 64 + (c0 ^ ((pos & 7) * 8))] = v;
    }
    __syncthreads();

    int l = t & 63, w = t >> 6;          // w = 0..7 = pixel row
    int quad = l >> 4, ln = l & 15;
    int px = w * 16 + ln;                // px = row-major pixel id (row w, col ln)
    int hh = h0 + w, ww = w0 + ln;

    // ---- phase 1: offset conv MFMA (M=128, N=32, K=576), B from pgwF coalesced ----
    {
        f32x4 o0 = {0.f, 0.f, 0.f, 0.f}, o1 = {0.f, 0.f, 0.f, 0.f};
#pragma unroll
        for (int kb = 0; kb < 18; ++kb) {
            int q = kb >> 1;
            int kh = q / 3, kw = q - 3 * (q / 3);
            short8 b0 = *(const short8*)&pgwF[(kb * 2 + 0) * 512 + l * 8];   // lane*16B
            short8 b1 = *(const short8*)&pgwF[(kb * 2 + 1) * 512 + l * 8];
            int aoff = (w + kh + 1) * 20 + (ln + kw + 1);
            int c0 = (kb & 1) * 32 + quad * 8;
            short8 af = *(const short8*)&patch[aoff * 64 + (c0 ^ ((aoff & 7) * 8))];
            o0 = __builtin_amdgcn_mfma_f32_16x16x32_bf16(af, b0, o0, 0, 0, 0);
            o1 = __builtin_amdgcn_mfma_f32_16x16x32_bf16(af, b1, o1, 0, 0, 0);
        }
#pragma unroll
        for (int tile = 0; tile < 2; ++tile) {
            int p = tile * 16 + ln;
            f32x4 a = tile ? o1 : o0;
            if (p < 27) {
                float bo = pg_b[p];
#pragma unroll
                for (int i = 0; i < 4; ++i) {
                    int wpx = w * 16 + quad * 4 + i;
                    float v = a[i] + bo;
                    if (p >= 18) v = 1.f / (1.f + expf(-v));
                    P_s[p * 129 + wpx] = v;
                }
            }
        }
    }
    __syncthreads();

    // ---- phase 2: sampling + main GEMM (M=128,N=64,K=576), B from wtF coalesced ----
    f32x4 acc[4];
#pragma unroll
    for (int nt = 0; nt < 4; ++nt) acc[nt] = (f32x4){0.f, 0.f, 0.f, 0.f};

    for (int kk = 0; kk < 9; ++kk) {
        // B fragments: coalesced lane*16B loads (L1/L2-hot)
        short8 bfr[2][4];
#pragma unroll
        for (int kb = 0; kb < 2; ++kb)
#pragma unroll
            for (int nt = 0; nt < 4; ++nt)
                bfr[kb][nt] = *(const short8*)&wtF[((kk * 2 + kb) * 4 + nt) * 512 + l * 8];

        // bilinear params from LDS (R12 body; stride 129)
        int ki = kk / 3, kj = kk - 3 * (kk / 3);
        float dyv = P_s[(2 * kk) * 129 + px];
        float dxv = P_s[(2 * kk + 1) * 129 + px];
        float m   = P_s[(18 + kk) * 129 + px];
        float ys = (float)(hh - 1 + ki) + dyv;
        float xs = (float)(ww - 1 + kj) + dxv;
        float y0f = floorf(ys), x0f = floorf(xs);
        int y0 = (int)y0f, x0 = (int)x0f;
        float ly = ys - y0f, lx = xs - x0f;
        float v0y = ((unsigned)y0 < 128u) ? 1.f : 0.f;
        float v1y = ((unsigned)(y0 + 1) < 128u) ? 1.f : 0.f;
        float v0x = ((unsigned)x0 < 128u) ? 1.f : 0.f;
        float v1x = ((unsigned)(x0 + 1) < 128u) ? 1.f : 0.f;
        float w00 = (1.f - ly) * (1.f - lx) * v0y * v0x * m;
        float w01 = (1.f - ly) * lx * v0y * v1x * m;
        float w10 = ly * (1.f - lx) * v1y * v0x * m;
        float w11 = ly * lx * v1y * v1x * m;
        int ly0 = y0 - base_y, lx0 = x0 - base_x;
        bool inp = ((unsigned)ly0 < 12u) && ((unsigned)lx0 < 18u);

        uint4 r[2][4];
        if (inp) {
            int pos = ly0 * 20 + lx0;
#pragma unroll
            for (int kb = 0; kb < 2; ++kb) {
                int c0 = kb * 32 + quad * 8;
                r[kb][0] = *(const uint4*)&patch[pos * 64 + (c0 ^ ((pos & 7) * 8))];
                r[kb][1] = *(const uint4*)&patch[(pos + 1) * 64 + (c0 ^ (((pos + 1) & 7) * 8))];
                r[kb][2] = *(const uint4*)&patch[(pos + 20) * 64 + (c0 ^ (((pos + 20) & 7) * 8))];
                r[kb][3] = *(const uint4*)&patch[(pos + 21) * 64 + (c0 ^ (((pos + 21) & 7) * 8))];
            }
        } else {   // rare (|offset| >= 1): direct xb reads, clamped corners
            int y0c = min(max(y0, 0), 127), y1c = min(max(y0 + 1, 0), 127);
            int x0c = min(max(x0, 0), 127), x1c = min(max(x0 + 1, 0), 127);
            int base00 = (y0c * 128 + x0c) * 64;
            int dxo = (x1c - x0c) * 64, dyo = (y1c - y0c) * 8192;
#pragma unroll
            for (int kb = 0; kb < 2; ++kb) {
                int c0 = kb * 32 + quad * 8;
                r[kb][0] = *(const uint4*)&xbb[base00 + c0];
                r[kb][1] = *(const uint4*)&xbb[base00 + dxo + c0];
                r[kb][2] = *(const uint4*)&xbb[base00 + dyo + c0];
                r[kb][3] = *(const uint4*)&xbb[base00 + dyo + dxo + c0];
            }
        }

        // packed-f32 bilinear: 2 channels per step; v_pk_mul/fma_f32 + v_cvt_pk_bf16_f32
        f32x2 W00 = {w00, w00}, W01 = {w01, w01}, W10 = {w10, w10}, W11 = {w11, w11};
        short8 af[2];
#pragma unroll
        for (int kb = 0; kb < 2; ++kb) {
            union { unsigned u[4]; short8 s; } afu;
#pragma unroll
            for (int p = 0; p < 4; ++p) {
                f32x2 v = W00 * unpk_bf16(uget(r[kb][0], p))
                        + W01 * unpk_bf16(uget(r[kb][1], p))
                        + W10 * unpk_bf16(uget(r[kb][2], p))
                        + W11 * unpk_bf16(uget(r[kb][3], p));
                afu.u[p] = cvt_pk_bf16(v);
            }
            af[kb] = afu.s;
        }

#pragma unroll
        for (int kb = 0; kb < 2; ++kb)
#pragma unroll
            for (int nt = 0; nt < 4; ++nt)
                acc[nt] = __builtin_amdgcn_mfma_f32_16x16x32_bf16(af[kb], bfr[kb][nt], acc[nt], 0, 0, 0);
    }

    // ---- epilogue: lane's 4 D-rows per nt = row w, cols quad*4..+3 -> float4 ----
    int ehh = h0 + w, eww = w0 + quad * 4;
#pragma unroll
    for (int nt = 0; nt < 4; ++nt) {
        int o = nt * 16 + ln;
        float bo = bias[o];
        float4 v;
        v.x = acc[nt][0] + bo; v.y = acc[nt][1] + bo;
        v.z = acc[nt][2] + bo; v.w = acc[nt][3] + bo;
        *(float4*)&out[((size_t)b * 64 + o) * 16384 + ehh * 128 + eww] = v;
    }
}

extern "C" void kernel_launch(void* const* d_in, const int* in_sizes, int n_in,
                              void* d_out, int out_size, void* d_ws, size_t ws_size,
                              hipStream_t stream) {
    const float* x      = (const float*)d_in[0];
    const float* weight = (const float*)d_in[1];
    const float* bias   = (const float*)d_in[2];
    const float* pg_w   = (const float*)d_in[3];
    const float* pg_b   = (const float*)d_in[4];
    float* out = (float*)d_out;

    unsigned short* xbB  = (unsigned short*)d_ws;        // 4*16384*64 bf16 (8.39 MB)
    unsigned short* wtF  = xbB + (size_t)4 * 16384 * 64; // 36,864 bf16 (fragment order)
    unsigned short* pgwF = wtF + 36864;                  // 18,432 bf16 (fragment order)

    k_nhwc<<<2048, 256, 0, stream>>>(x, xbB);
    k_pack_w<<<216, 256, 0, stream>>>(weight, pg_w, wtF, pgwF);
    k_fused<<<512, 512, 0, stream>>>(xbB, pgwF, pg_b, wtF, bias, out);
}

// Round 2
// 100.541 us; speedup vs baseline: 1.0472x; 1.0206x over previous
//
#include <hip/hip_runtime.h>
#include <hip/hip_fp16.h>
#include <math.h>

// B=4, C=64, H=W=128, O=64, K=3, pad=1, stride=1
// Round-15: R14 (green, 102.6us) + ONE delta: whole pipeline bf16 -> f16.
// Bilinear weighted sum now runs directly on packed f16 (v_pk_fma_f16 / __hfma2):
// 4 insts per channel-pair vs 13 (no unpack, no cvt_pk) -> ~30% fewer phase-2 VALU insts.
// MFMA switches to mfma_f32_16x16x32_f16 (same shape/layout/rate). f16 mantissa (2^-11)
// beats bf16 (2^-8); accumulators stay f32 -> absmax should improve.
// Geometry, staging, LDS swizzle, both GEMM structures verbatim from R14.
// Known harness floor ~52us (268MB ws re-poison fill @ ~6TB/s + restores) is inside dur_us.
// ws: xh 8.39 MB + wtF + pgwF (~8.5 MB)

typedef __attribute__((ext_vector_type(8))) short short8;     // 8 f16 bit-patterns (A/B frag)
typedef __attribute__((ext_vector_type(8))) _Float16 f16x8;   // MFMA A/B frag (4 VGPRs)
typedef __attribute__((ext_vector_type(4))) float f32x4;      // C/D frag

__device__ __forceinline__ unsigned short f2h(float f) {   // RNE f32->f16
    union { __half h; unsigned short s; } v; v.h = __float2half_rn(f); return v.s;
}
__device__ __forceinline__ f16x8 s2f(short8 s) {
    union { short8 s; f16x8 f; } u; u.s = s; return u.f;
}
__device__ __forceinline__ __half2 u2h2(unsigned u) {
    union { unsigned u; __half2 h; } v; v.u = u; return v.h;
}
__device__ __forceinline__ unsigned h22u(__half2 h) {
    union { __half2 h; unsigned u; } v; v.h = h; return v.u;
}
__device__ __forceinline__ unsigned uget(const uint4& v, int p) {
    return p == 0 ? v.x : p == 1 ? v.y : p == 2 ? v.z : v.w;
}

// ---------------- K0: NCHW fp32 -> NHWC f16 (structure exact R12) ----------------
__global__ __launch_bounds__(256) void k_nhwc(const float* __restrict__ x,
                                              unsigned short* __restrict__ xh) {
    __shared__ float tile[64][33];
    int bid = blockIdx.x;
    int b = bid >> 9, h = (bid >> 2) & 127, w0 = (bid & 3) * 32;
    int t = threadIdx.x;
    for (int idx = t; idx < 2048; idx += 256) {
        int c = idx >> 5, w = idx & 31;
        tile[c][w] = x[((b * 64 + c) * 128 + h) * 128 + w0 + w];
    }
    __syncthreads();
    {
        int wl = t >> 3, c0 = (t & 7) * 8;
        short8 v;
#pragma unroll
        for (int e = 0; e < 8; ++e) v[e] = (short)f2h(tile[c0 + e][wl]);
        *(short8*)&xh[(((size_t)b * 128 + h) * 128 + w0 + wl) * 64 + c0] = v;
    }
}

// ---------------- K1: pack weights to f16, FRAGMENT order (structure exact R12) ----------------
__global__ __launch_bounds__(256) void k_pack_w(const float* __restrict__ weight,
                                                const float* __restrict__ pg_w,
                                                unsigned short* __restrict__ wtF,
                                                unsigned short* __restrict__ pgwF) {
    int idx = blockIdx.x * 256 + threadIdx.x;
    if (idx < 36864) {
        int e = idx & 7, l = (idx >> 3) & 63, grp = idx >> 9;   // grp 0..71
        int nt = grp & 3, kb = (grp >> 2) & 1, kk = grp >> 3;
        int ln = l & 15, quad = l >> 4;
        int o = nt * 16 + ln;
        int c = kb * 32 + quad * 8 + e;
        wtF[idx] = f2h(weight[(o * 64 + c) * 9 + kk]);
    }
    int i2 = idx - 36864;
    if (i2 >= 0 && i2 < 18432) {
        int e = i2 & 7, l = (i2 >> 3) & 63, grp = i2 >> 9;      // grp 0..35
        int tile = grp & 1, kb = grp >> 1;
        int ln = l & 15, quad = l >> 4;
        int p = tile * 16 + ln;
        int k = kb * 32 + quad * 8 + e;
        float v = 0.f;
        if (p < 27) {
            int q = k >> 6, c = k & 63;
            v = pg_w[(p * 64 + c) * 9 + q];
        }
        pgwF[i2] = f2h(v);
    }
}

// ---------------- K2: fused offset-conv + deformable conv, 8x16 tile ----------------
// 512 blocks (b x 16 x 8), tile = 8 rows x 16 cols. 512 threads = 8 waves; wave w = row w.
__global__ __launch_bounds__(512) void k_fused(const unsigned short* __restrict__ xh,
                                               const unsigned short* __restrict__ pgwF,
                                               const float* __restrict__ pg_b,
                                               const unsigned short* __restrict__ wtF,
                                               const float* __restrict__ bias,
                                               float* __restrict__ out) {
    __shared__ unsigned short patch[260 * 64];   // 33.3 KB [pos=yy*20+xx][c ^ (pos&7)*8]
    __shared__ float P_s[27 * 129];              // 13.9 KB [param][px], stride 129

    int bid = blockIdx.x;
    int b  = bid >> 7;
    int h0 = ((bid >> 3) & 15) * 8;
    int w0 = (bid & 7) * 16;
    int t = threadIdx.x;
    int base_y = h0 - 2, base_x = w0 - 2;
    const unsigned short* xbb = xh + (size_t)b * 16384 * 64;

    // ---- phase 0: stage patch from xh; 2080 b128 chunks, coalesced ----
    for (int i = t; i < 2080; i += 512) {
        int yy = i / 160;                 // 8 chunks per 20-col row
        int r  = i - yy * 160;
        int xx = r >> 3;
        int c0 = (r & 7) * 8;
        int gy = base_y + yy, gx = base_x + xx;
        int pos = yy * 20 + xx;
        short8 v = (short8)0;
        if (((unsigned)gy < 128u) && ((unsigned)gx < 128u))
            v = *(const short8*)&xbb[(gy * 128 + gx) * 64 + c0];
        *(short8*)&patch[pos * 64 + (c0 ^ ((pos & 7) * 8))] = v;
    }
    __syncthreads();

    int l = t & 63, w = t >> 6;          // w = 0..7 = pixel row
    int quad = l >> 4, ln = l & 15;
    int px = w * 16 + ln;                // px = row-major pixel id (row w, col ln)
    int hh = h0 + w, ww = w0 + ln;

    // ---- phase 1: offset conv MFMA (M=128, N=32, K=576), B from pgwF coalesced ----
    {
        f32x4 o0 = {0.f, 0.f, 0.f, 0.f}, o1 = {0.f, 0.f, 0.f, 0.f};
#pragma unroll
        for (int kb = 0; kb < 18; ++kb) {
            int q = kb >> 1;
            int kh = q / 3, kw = q - 3 * (q / 3);
            short8 b0 = *(const short8*)&pgwF[(kb * 2 + 0) * 512 + l * 8];   // lane*16B
            short8 b1 = *(const short8*)&pgwF[(kb * 2 + 1) * 512 + l * 8];
            int aoff = (w + kh + 1) * 20 + (ln + kw + 1);
            int c0 = (kb & 1) * 32 + quad * 8;
            short8 af = *(const short8*)&patch[aoff * 64 + (c0 ^ ((aoff & 7) * 8))];
            o0 = __builtin_amdgcn_mfma_f32_16x16x32_f16(s2f(af), s2f(b0), o0, 0, 0, 0);
            o1 = __builtin_amdgcn_mfma_f32_16x16x32_f16(s2f(af), s2f(b1), o1, 0, 0, 0);
        }
#pragma unroll
        for (int tile = 0; tile < 2; ++tile) {
            int p = tile * 16 + ln;
            f32x4 a = tile ? o1 : o0;
            if (p < 27) {
                float bo = pg_b[p];
#pragma unroll
                for (int i = 0; i < 4; ++i) {
                    int wpx = w * 16 + quad * 4 + i;
                    float v = a[i] + bo;
                    if (p >= 18) v = 1.f / (1.f + expf(-v));
                    P_s[p * 129 + wpx] = v;
                }
            }
        }
    }
    __syncthreads();

    // ---- phase 2: sampling + main GEMM (M=128,N=64,K=576), B from wtF coalesced ----
    f32x4 acc[4];
#pragma unroll
    for (int nt = 0; nt < 4; ++nt) acc[nt] = (f32x4){0.f, 0.f, 0.f, 0.f};

    for (int kk = 0; kk < 9; ++kk) {
        // B fragments: coalesced lane*16B loads (L1/L2-hot)
        short8 bfr[2][4];
#pragma unroll
        for (int kb = 0; kb < 2; ++kb)
#pragma unroll
            for (int nt = 0; nt < 4; ++nt)
                bfr[kb][nt] = *(const short8*)&wtF[((kk * 2 + kb) * 4 + nt) * 512 + l * 8];

        // bilinear params from LDS (R12 body; stride 129)
        int ki = kk / 3, kj = kk - 3 * (kk / 3);
        float dyv = P_s[(2 * kk) * 129 + px];
        float dxv = P_s[(2 * kk + 1) * 129 + px];
        float m   = P_s[(18 + kk) * 129 + px];
        float ys = (float)(hh - 1 + ki) + dyv;
        float xs = (float)(ww - 1 + kj) + dxv;
        float y0f = floorf(ys), x0f = floorf(xs);
        int y0 = (int)y0f, x0 = (int)x0f;
        float ly = ys - y0f, lx = xs - x0f;
        float v0y = ((unsigned)y0 < 128u) ? 1.f : 0.f;
        float v1y = ((unsigned)(y0 + 1) < 128u) ? 1.f : 0.f;
        float v0x = ((unsigned)x0 < 128u) ? 1.f : 0.f;
        float v1x = ((unsigned)(x0 + 1) < 128u) ? 1.f : 0.f;
        float w00 = (1.f - ly) * (1.f - lx) * v0y * v0x * m;
        float w01 = (1.f - ly) * lx * v0y * v1x * m;
        float w10 = ly * (1.f - lx) * v1y * v0x * m;
        float w11 = ly * lx * v1y * v1x * m;
        int ly0 = y0 - base_y, lx0 = x0 - base_x;
        bool inp = ((unsigned)ly0 < 12u) && ((unsigned)lx0 < 18u);

        uint4 r[2][4];
        if (inp) {
            int pos = ly0 * 20 + lx0;
#pragma unroll
            for (int kb = 0; kb < 2; ++kb) {
                int c0 = kb * 32 + quad * 8;
                r[kb][0] = *(const uint4*)&patch[pos * 64 + (c0 ^ ((pos & 7) * 8))];
                r[kb][1] = *(const uint4*)&patch[(pos + 1) * 64 + (c0 ^ (((pos + 1) & 7) * 8))];
                r[kb][2] = *(const uint4*)&patch[(pos + 20) * 64 + (c0 ^ (((pos + 20) & 7) * 8))];
                r[kb][3] = *(const uint4*)&patch[(pos + 21) * 64 + (c0 ^ (((pos + 21) & 7) * 8))];
            }
        } else {   // rare (|offset| >= 1): direct xh reads, clamped corners
            int y0c = min(max(y0, 0), 127), y1c = min(max(y0 + 1, 0), 127);
            int x0c = min(max(x0, 0), 127), x1c = min(max(x0 + 1, 0), 127);
            int base00 = (y0c * 128 + x0c) * 64;
            int dxo = (x1c - x0c) * 64, dyo = (y1c - y0c) * 8192;
#pragma unroll
            for (int kb = 0; kb < 2; ++kb) {
                int c0 = kb * 32 + quad * 8;
                r[kb][0] = *(const uint4*)&xbb[base00 + c0];
                r[kb][1] = *(const uint4*)&xbb[base00 + dxo + c0];
                r[kb][2] = *(const uint4*)&xbb[base00 + dyo + c0];
                r[kb][3] = *(const uint4*)&xbb[base00 + dyo + dxo + c0];
            }
        }

        // packed-f16 bilinear: 2 channels per step; pure v_pk_mul/fma_f16, no unpack/repack
        __half2 W00 = __float2half2_rn(w00), W01 = __float2half2_rn(w01);
        __half2 W10 = __float2half2_rn(w10), W11 = __float2half2_rn(w11);
        f16x8 af[2];
#pragma unroll
        for (int kb = 0; kb < 2; ++kb) {
            union { unsigned u[4]; f16x8 f; } afu;
#pragma unroll
            for (int p = 0; p < 4; ++p) {
                __half2 v = __hmul2(W00, u2h2(uget(r[kb][0], p)));
                v = __hfma2(W01, u2h2(uget(r[kb][1], p)), v);
                v = __hfma2(W10, u2h2(uget(r[kb][2], p)), v);
                v = __hfma2(W11, u2h2(uget(r[kb][3], p)), v);
                afu.u[p] = h22u(v);
            }
            af[kb] = afu.f;
        }

#pragma unroll
        for (int kb = 0; kb < 2; ++kb)
#pragma unroll
            for (int nt = 0; nt < 4; ++nt)
                acc[nt] = __builtin_amdgcn_mfma_f32_16x16x32_f16(af[kb], s2f(bfr[kb][nt]), acc[nt], 0, 0, 0);
    }

    // ---- epilogue: lane's 4 D-rows per nt = row w, cols quad*4..+3 -> float4 ----
    int ehh = h0 + w, eww = w0 + quad * 4;
#pragma unroll
    for (int nt = 0; nt < 4; ++nt) {
        int o = nt * 16 + ln;
        float bo = bias[o];
        float4 v;
        v.x = acc[nt][0] + bo; v.y = acc[nt][1] + bo;
        v.z = acc[nt][2] + bo; v.w = acc[nt][3] + bo;
        *(float4*)&out[((size_t)b * 64 + o) * 16384 + ehh * 128 + eww] = v;
    }
}

extern "C" void kernel_launch(void* const* d_in, const int* in_sizes, int n_in,
                              void* d_out, int out_size, void* d_ws, size_t ws_size,
                              hipStream_t stream) {
    const float* x      = (const float*)d_in[0];
    const float* weight = (const float*)d_in[1];
    const float* bias   = (const float*)d_in[2];
    const float* pg_w   = (const float*)d_in[3];
    const float* pg_b   = (const float*)d_in[4];
    float* out = (float*)d_out;

    unsigned short* xhB  = (unsigned short*)d_ws;        // 4*16384*64 f16 (8.39 MB)
    unsigned short* wtF  = xhB + (size_t)4 * 16384 * 64; // 36,864 f16 (fragment order)
    unsigned short* pgwF = wtF + 36864;                  // 18,432 f16 (fragment order)

    k_nhwc<<<2048, 256, 0, stream>>>(x, xhB);
    k_pack_w<<<216, 256, 0, stream>>>(weight, pg_w, wtF, pgwF);
    k_fused<<<512, 512, 0, stream>>>(xhB, pgwF, pg_b, wtF, bias, out);
}

// Round 3
// 99.665 us; speedup vs baseline: 1.0564x; 1.0088x over previous
//
#include <hip/hip_runtime.h>
#include <hip/hip_fp16.h>
#include <math.h>

// B=4, C=64, H=W=128, O=64, K=3, pad=1, stride=1
// Round-16: R15 (green, 100.5us) + ONE delta: LDS patch layout [pos][c^swz] ->
// channel-group-major [cg][pos][8ch] with padded plane stride 2088 shorts (4176B).
// Conflict-freedom now structural (consecutive pos -> sequential 16B slots; plane
// stride 4176B -> 8 distinct bank offsets), so corner reads become ONE base addr
// (quad*2088 + pos*8) + immediate offsets {0,+8,+160,+168} (+8352 per kb, folds
// into ds_read offset:). Cuts ~45 -> ~3 addr VALU insts per kk in phase 2.
// Everything else verbatim from R15 (f16 pipeline, pk-f16 bilinear, MFMA f16).
// Known harness floor ~52us (268MB ws re-poison fill @ ~6TB/s + restores) is inside dur_us.
// ws: xh 8.39 MB + wtF + pgwF (~8.5 MB)

typedef __attribute__((ext_vector_type(8))) short short8;     // 8 f16 bit-patterns (A/B frag)
typedef __attribute__((ext_vector_type(8))) _Float16 f16x8;   // MFMA A/B frag (4 VGPRs)
typedef __attribute__((ext_vector_type(4))) float f32x4;      // C/D frag

#define PSTR 2088   // padded plane stride in shorts (260 pos * 8 ch + 8 pad)

__device__ __forceinline__ unsigned short f2h(float f) {   // RNE f32->f16
    union { __half h; unsigned short s; } v; v.h = __float2half_rn(f); return v.s;
}
__device__ __forceinline__ f16x8 s2f(short8 s) {
    union { short8 s; f16x8 f; } u; u.s = s; return u.f;
}
__device__ __forceinline__ __half2 u2h2(unsigned u) {
    union { unsigned u; __half2 h; } v; v.u = u; return v.h;
}
__device__ __forceinline__ unsigned h22u(__half2 h) {
    union { __half2 h; unsigned u; } v; v.h = h; return v.u;
}
__device__ __forceinline__ unsigned uget(const uint4& v, int p) {
    return p == 0 ? v.x : p == 1 ? v.y : p == 2 ? v.z : v.w;
}

// ---------------- K0: NCHW fp32 -> NHWC f16 (structure exact R12) ----------------
__global__ __launch_bounds__(256) void k_nhwc(const float* __restrict__ x,
                                              unsigned short* __restrict__ xh) {
    __shared__ float tile[64][33];
    int bid = blockIdx.x;
    int b = bid >> 9, h = (bid >> 2) & 127, w0 = (bid & 3) * 32;
    int t = threadIdx.x;
    for (int idx = t; idx < 2048; idx += 256) {
        int c = idx >> 5, w = idx & 31;
        tile[c][w] = x[((b * 64 + c) * 128 + h) * 128 + w0 + w];
    }
    __syncthreads();
    {
        int wl = t >> 3, c0 = (t & 7) * 8;
        short8 v;
#pragma unroll
        for (int e = 0; e < 8; ++e) v[e] = (short)f2h(tile[c0 + e][wl]);
        *(short8*)&xh[(((size_t)b * 128 + h) * 128 + w0 + wl) * 64 + c0] = v;
    }
}

// ---------------- K1: pack weights to f16, FRAGMENT order (structure exact R12) ----------------
__global__ __launch_bounds__(256) void k_pack_w(const float* __restrict__ weight,
                                                const float* __restrict__ pg_w,
                                                unsigned short* __restrict__ wtF,
                                                unsigned short* __restrict__ pgwF) {
    int idx = blockIdx.x * 256 + threadIdx.x;
    if (idx < 36864) {
        int e = idx & 7, l = (idx >> 3) & 63, grp = idx >> 9;   // grp 0..71
        int nt = grp & 3, kb = (grp >> 2) & 1, kk = grp >> 3;
        int ln = l & 15, quad = l >> 4;
        int o = nt * 16 + ln;
        int c = kb * 32 + quad * 8 + e;
        wtF[idx] = f2h(weight[(o * 64 + c) * 9 + kk]);
    }
    int i2 = idx - 36864;
    if (i2 >= 0 && i2 < 18432) {
        int e = i2 & 7, l = (i2 >> 3) & 63, grp = i2 >> 9;      // grp 0..35
        int tile = grp & 1, kb = grp >> 1;
        int ln = l & 15, quad = l >> 4;
        int p = tile * 16 + ln;
        int k = kb * 32 + quad * 8 + e;
        float v = 0.f;
        if (p < 27) {
            int q = k >> 6, c = k & 63;
            v = pg_w[(p * 64 + c) * 9 + q];
        }
        pgwF[i2] = f2h(v);
    }
}

// ---------------- K2: fused offset-conv + deformable conv, 8x16 tile ----------------
// 512 blocks (b x 16 x 8), tile = 8 rows x 16 cols. 512 threads = 8 waves; wave w = row w.
__global__ __launch_bounds__(512) void k_fused(const unsigned short* __restrict__ xh,
                                               const unsigned short* __restrict__ pgwF,
                                               const float* __restrict__ pg_b,
                                               const unsigned short* __restrict__ wtF,
                                               const float* __restrict__ bias,
                                               float* __restrict__ out) {
    __shared__ unsigned short patch[8 * PSTR];   // 32.6 KB [cg][pos][8ch], plane pad +8
    __shared__ float P_s[27 * 129];              // 13.9 KB [param][px], stride 129

    int bid = blockIdx.x;
    int b  = bid >> 7;
    int h0 = ((bid >> 3) & 15) * 8;
    int w0 = (bid & 7) * 16;
    int t = threadIdx.x;
    int base_y = h0 - 2, base_x = w0 - 2;
    const unsigned short* xbb = xh + (size_t)b * 16384 * 64;

    // ---- phase 0: stage patch from xh; 2080 b128 chunks, coalesced ----
    for (int i = t; i < 2080; i += 512) {
        int yy = i / 160;                 // 8 chunks per 20-col row
        int r  = i - yy * 160;
        int xx = r >> 3;
        int cg = r & 7;
        int gy = base_y + yy, gx = base_x + xx;
        int pos = yy * 20 + xx;
        short8 v = (short8)0;
        if (((unsigned)gy < 128u) && ((unsigned)gx < 128u))
            v = *(const short8*)&xbb[(gy * 128 + gx) * 64 + cg * 8];
        *(short8*)&patch[cg * PSTR + pos * 8] = v;
    }
    __syncthreads();

    int l = t & 63, w = t >> 6;          // w = 0..7 = pixel row
    int quad = l >> 4, ln = l & 15;
    int px = w * 16 + ln;                // px = row-major pixel id (row w, col ln)
    int hh = h0 + w, ww = w0 + ln;

    // ---- phase 1: offset conv MFMA (M=128, N=32, K=576), B from pgwF coalesced ----
    {
        f32x4 o0 = {0.f, 0.f, 0.f, 0.f}, o1 = {0.f, 0.f, 0.f, 0.f};
#pragma unroll
        for (int kb = 0; kb < 18; ++kb) {
            int q = kb >> 1;
            int kh = q / 3, kw = q - 3 * (q / 3);
            short8 b0 = *(const short8*)&pgwF[(kb * 2 + 0) * 512 + l * 8];   // lane*16B
            short8 b1 = *(const short8*)&pgwF[(kb * 2 + 1) * 512 + l * 8];
            int aoff = (w + kh + 1) * 20 + (ln + kw + 1);
            int cg = (kb & 1) * 4 + quad;
            short8 af = *(const short8*)&patch[cg * PSTR + aoff * 8];
            o0 = __builtin_amdgcn_mfma_f32_16x16x32_f16(s2f(af), s2f(b0), o0, 0, 0, 0);
            o1 = __builtin_amdgcn_mfma_f32_16x16x32_f16(s2f(af), s2f(b1), o1, 0, 0, 0);
        }
#pragma unroll
        for (int tile = 0; tile < 2; ++tile) {
            int p = tile * 16 + ln;
            f32x4 a = tile ? o1 : o0;
            if (p < 27) {
                float bo = pg_b[p];
#pragma unroll
                for (int i = 0; i < 4; ++i) {
                    int wpx = w * 16 + quad * 4 + i;
                    float v = a[i] + bo;
                    if (p >= 18) v = 1.f / (1.f + expf(-v));
                    P_s[p * 129 + wpx] = v;
                }
            }
        }
    }
    __syncthreads();

    // ---- phase 2: sampling + main GEMM (M=128,N=64,K=576), B from wtF coalesced ----
    f32x4 acc[4];
#pragma unroll
    for (int nt = 0; nt < 4; ++nt) acc[nt] = (f32x4){0.f, 0.f, 0.f, 0.f};

    int qbase = quad * PSTR;             // per-thread constant plane base

    for (int kk = 0; kk < 9; ++kk) {
        // B fragments: coalesced lane*16B loads (L1/L2-hot)
        short8 bfr[2][4];
#pragma unroll
        for (int kb = 0; kb < 2; ++kb)
#pragma unroll
            for (int nt = 0; nt < 4; ++nt)
                bfr[kb][nt] = *(const short8*)&wtF[((kk * 2 + kb) * 4 + nt) * 512 + l * 8];

        // bilinear params from LDS (R12 body; stride 129)
        int ki = kk / 3, kj = kk - 3 * (kk / 3);
        float dyv = P_s[(2 * kk) * 129 + px];
        float dxv = P_s[(2 * kk + 1) * 129 + px];
        float m   = P_s[(18 + kk) * 129 + px];
        float ys = (float)(hh - 1 + ki) + dyv;
        float xs = (float)(ww - 1 + kj) + dxv;
        float y0f = floorf(ys), x0f = floorf(xs);
        int y0 = (int)y0f, x0 = (int)x0f;
        float ly = ys - y0f, lx = xs - x0f;
        float v0y = ((unsigned)y0 < 128u) ? 1.f : 0.f;
        float v1y = ((unsigned)(y0 + 1) < 128u) ? 1.f : 0.f;
        float v0x = ((unsigned)x0 < 128u) ? 1.f : 0.f;
        float v1x = ((unsigned)(x0 + 1) < 128u) ? 1.f : 0.f;
        float w00 = (1.f - ly) * (1.f - lx) * v0y * v0x * m;
        float w01 = (1.f - ly) * lx * v0y * v1x * m;
        float w10 = ly * (1.f - lx) * v1y * v0x * m;
        float w11 = ly * lx * v1y * v1x * m;
        int ly0 = y0 - base_y, lx0 = x0 - base_x;
        bool inp = ((unsigned)ly0 < 12u) && ((unsigned)lx0 < 18u);

        uint4 r[2][4];
        if (inp) {
            int pb = qbase + (ly0 * 20 + lx0) * 8;   // one base; corners = imm offsets
#pragma unroll
            for (int kb = 0; kb < 2; ++kb) {
                int base = pb + kb * 4 * PSTR;       // kb term folds to imm in ds_read
                r[kb][0] = *(const uint4*)&patch[base];
                r[kb][1] = *(const uint4*)&patch[base + 8];
                r[kb][2] = *(const uint4*)&patch[base + 160];
                r[kb][3] = *(const uint4*)&patch[base + 168];
            }
        } else {   // rare (|offset| >= 1): direct xh reads, clamped corners
            int y0c = min(max(y0, 0), 127), y1c = min(max(y0 + 1, 0), 127);
            int x0c = min(max(x0, 0), 127), x1c = min(max(x0 + 1, 0), 127);
            int base00 = (y0c * 128 + x0c) * 64;
            int dxo = (x1c - x0c) * 64, dyo = (y1c - y0c) * 8192;
#pragma unroll
            for (int kb = 0; kb < 2; ++kb) {
                int c0 = kb * 32 + quad * 8;
                r[kb][0] = *(const uint4*)&xbb[base00 + c0];
                r[kb][1] = *(const uint4*)&xbb[base00 + dxo + c0];
                r[kb][2] = *(const uint4*)&xbb[base00 + dyo + c0];
                r[kb][3] = *(const uint4*)&xbb[base00 + dyo + dxo + c0];
            }
        }

        // packed-f16 bilinear: 2 channels per step; pure v_pk_mul/fma_f16, no unpack/repack
        __half2 W00 = __float2half2_rn(w00), W01 = __float2half2_rn(w01);
        __half2 W10 = __float2half2_rn(w10), W11 = __float2half2_rn(w11);
        f16x8 af[2];
#pragma unroll
        for (int kb = 0; kb < 2; ++kb) {
            union { unsigned u[4]; f16x8 f; } afu;
#pragma unroll
            for (int p = 0; p < 4; ++p) {
                __half2 v = __hmul2(W00, u2h2(uget(r[kb][0], p)));
                v = __hfma2(W01, u2h2(uget(r[kb][1], p)), v);
                v = __hfma2(W10, u2h2(uget(r[kb][2], p)), v);
                v = __hfma2(W11, u2h2(uget(r[kb][3], p)), v);
                afu.u[p] = h22u(v);
            }
            af[kb] = afu.f;
        }

#pragma unroll
        for (int kb = 0; kb < 2; ++kb)
#pragma unroll
            for (int nt = 0; nt < 4; ++nt)
                acc[nt] = __builtin_amdgcn_mfma_f32_16x16x32_f16(af[kb], s2f(bfr[kb][nt]), acc[nt], 0, 0, 0);
    }

    // ---- epilogue: lane's 4 D-rows per nt = row w, cols quad*4..+3 -> float4 ----
    int ehh = h0 + w, eww = w0 + quad * 4;
#pragma unroll
    for (int nt = 0; nt < 4; ++nt) {
        int o = nt * 16 + ln;
        float bo = bias[o];
        float4 v;
        v.x = acc[nt][0] + bo; v.y = acc[nt][1] + bo;
        v.z = acc[nt][2] + bo; v.w = acc[nt][3] + bo;
        *(float4*)&out[((size_t)b * 64 + o) * 16384 + ehh * 128 + eww] = v;
    }
}

extern "C" void kernel_launch(void* const* d_in, const int* in_sizes, int n_in,
                              void* d_out, int out_size, void* d_ws, size_t ws_size,
                              hipStream_t stream) {
    const float* x      = (const float*)d_in[0];
    const float* weight = (const float*)d_in[1];
    const float* bias   = (const float*)d_in[2];
    const float* pg_w   = (const float*)d_in[3];
    const float* pg_b   = (const float*)d_in[4];
    float* out = (float*)d_out;

    unsigned short* xhB  = (unsigned short*)d_ws;        // 4*16384*64 f16 (8.39 MB)
    unsigned short* wtF  = xhB + (size_t)4 * 16384 * 64; // 36,864 f16 (fragment order)
    unsigned short* pgwF = wtF + 36864;                  // 18,432 f16 (fragment order)

    k_nhwc<<<2048, 256, 0, stream>>>(x, xhB);
    k_pack_w<<<216, 256, 0, stream>>>(weight, pg_w, wtF, pgwF);
    k_fused<<<512, 512, 0, stream>>>(xhB, pgwF, pg_b, wtF, bias, out);
}

// Round 4
// 97.201 us; speedup vs baseline: 1.0832x; 1.0254x over previous
//
#include <hip/hip_runtime.h>
#include <hip/hip_fp16.h>
#include <math.h>

// B=4, C=64, H=W=128, O=64, K=3, pad=1, stride=1
// Round-17: R16 (green, 99.7us) + ONE delta: merge k_nhwc + k_pack_w into a single
// dispatch k_prep (union grid 2048+216 blocks, branch on blockIdx.x; bodies verbatim).
// They are data-independent (both only feed k_fused): removes one kernel boundary
// and overlaps pack (~2us) inside the BW-bound transpose. No hot-path changes.
// Everything else verbatim from R16 (f16 pipeline, [cg][pos][8ch] LDS, imm-offset corners).
// Known harness floor ~52us (268MB ws re-poison fill @ ~6TB/s + restores) is inside dur_us.
// ws: xh 8.39 MB + wtF + pgwF (~8.5 MB)

typedef __attribute__((ext_vector_type(8))) short short8;     // 8 f16 bit-patterns (A/B frag)
typedef __attribute__((ext_vector_type(8))) _Float16 f16x8;   // MFMA A/B frag (4 VGPRs)
typedef __attribute__((ext_vector_type(4))) float f32x4;      // C/D frag

#define PSTR 2088   // padded plane stride in shorts (260 pos * 8 ch + 8 pad)

__device__ __forceinline__ unsigned short f2h(float f) {   // RNE f32->f16
    union { __half h; unsigned short s; } v; v.h = __float2half_rn(f); return v.s;
}
__device__ __forceinline__ f16x8 s2f(short8 s) {
    union { short8 s; f16x8 f; } u; u.s = s; return u.f;
}
__device__ __forceinline__ __half2 u2h2(unsigned u) {
    union { unsigned u; __half2 h; } v; v.u = u; return v.h;
}
__device__ __forceinline__ unsigned h22u(__half2 h) {
    union { __half2 h; unsigned u; } v; v.h = h; return v.u;
}
__device__ __forceinline__ unsigned uget(const uint4& v, int p) {
    return p == 0 ? v.x : p == 1 ? v.y : p == 2 ? v.z : v.w;
}

// ---------------- K0: merged prep: NCHW->NHWC f16 transpose  +  weight pack ----------------
// blocks 0..2047: transpose body (exact R16 k_nhwc). blocks 2048..2263: pack body
// (exact R16 k_pack_w with idx = (bid-2048)*256 + t; 216*256 = 55296 = 36864+18432).
__global__ __launch_bounds__(256) void k_prep(const float* __restrict__ x,
                                              unsigned short* __restrict__ xh,
                                              const float* __restrict__ weight,
                                              const float* __restrict__ pg_w,
                                              unsigned short* __restrict__ wtF,
                                              unsigned short* __restrict__ pgwF) {
    __shared__ float tile[64][33];
    int bid = blockIdx.x;
    int t = threadIdx.x;
    if (bid < 2048) {
        int b = bid >> 9, h = (bid >> 2) & 127, w0 = (bid & 3) * 32;
        for (int idx = t; idx < 2048; idx += 256) {
            int c = idx >> 5, w = idx & 31;
            tile[c][w] = x[((b * 64 + c) * 128 + h) * 128 + w0 + w];
        }
        __syncthreads();
        {
            int wl = t >> 3, c0 = (t & 7) * 8;
            short8 v;
#pragma unroll
            for (int e = 0; e < 8; ++e) v[e] = (short)f2h(tile[c0 + e][wl]);
            *(short8*)&xh[(((size_t)b * 128 + h) * 128 + w0 + wl) * 64 + c0] = v;
        }
    } else {
        int idx = (bid - 2048) * 256 + t;
        if (idx < 36864) {
            int e = idx & 7, l = (idx >> 3) & 63, grp = idx >> 9;   // grp 0..71
            int nt = grp & 3, kb = (grp >> 2) & 1, kk = grp >> 3;
            int ln = l & 15, quad = l >> 4;
            int o = nt * 16 + ln;
            int c = kb * 32 + quad * 8 + e;
            wtF[idx] = f2h(weight[(o * 64 + c) * 9 + kk]);
        }
        int i2 = idx - 36864;
        if (i2 >= 0 && i2 < 18432) {
            int e = i2 & 7, l = (i2 >> 3) & 63, grp = i2 >> 9;      // grp 0..35
            int tl = grp & 1, kb = grp >> 1;
            int ln = l & 15, quad = l >> 4;
            int p = tl * 16 + ln;
            int k = kb * 32 + quad * 8 + e;
            float v = 0.f;
            if (p < 27) {
                int q = k >> 6, c = k & 63;
                v = pg_w[(p * 64 + c) * 9 + q];
            }
            pgwF[i2] = f2h(v);
        }
    }
}

// ---------------- K2: fused offset-conv + deformable conv, 8x16 tile ----------------
// 512 blocks (b x 16 x 8), tile = 8 rows x 16 cols. 512 threads = 8 waves; wave w = row w.
__global__ __launch_bounds__(512) void k_fused(const unsigned short* __restrict__ xh,
                                               const unsigned short* __restrict__ pgwF,
                                               const float* __restrict__ pg_b,
                                               const unsigned short* __restrict__ wtF,
                                               const float* __restrict__ bias,
                                               float* __restrict__ out) {
    __shared__ unsigned short patch[8 * PSTR];   // 32.6 KB [cg][pos][8ch], plane pad +8
    __shared__ float P_s[27 * 129];              // 13.9 KB [param][px], stride 129

    int bid = blockIdx.x;
    int b  = bid >> 7;
    int h0 = ((bid >> 3) & 15) * 8;
    int w0 = (bid & 7) * 16;
    int t = threadIdx.x;
    int base_y = h0 - 2, base_x = w0 - 2;
    const unsigned short* xbb = xh + (size_t)b * 16384 * 64;

    // ---- phase 0: stage patch from xh; 2080 b128 chunks, coalesced ----
    for (int i = t; i < 2080; i += 512) {
        int yy = i / 160;                 // 8 chunks per 20-col row
        int r  = i - yy * 160;
        int xx = r >> 3;
        int cg = r & 7;
        int gy = base_y + yy, gx = base_x + xx;
        int pos = yy * 20 + xx;
        short8 v = (short8)0;
        if (((unsigned)gy < 128u) && ((unsigned)gx < 128u))
            v = *(const short8*)&xbb[(gy * 128 + gx) * 64 + cg * 8];
        *(short8*)&patch[cg * PSTR + pos * 8] = v;
    }
    __syncthreads();

    int l = t & 63, w = t >> 6;          // w = 0..7 = pixel row
    int quad = l >> 4, ln = l & 15;
    int px = w * 16 + ln;                // px = row-major pixel id (row w, col ln)
    int hh = h0 + w, ww = w0 + ln;

    // ---- phase 1: offset conv MFMA (M=128, N=32, K=576), B from pgwF coalesced ----
    {
        f32x4 o0 = {0.f, 0.f, 0.f, 0.f}, o1 = {0.f, 0.f, 0.f, 0.f};
#pragma unroll
        for (int kb = 0; kb < 18; ++kb) {
            int q = kb >> 1;
            int kh = q / 3, kw = q - 3 * (q / 3);
            short8 b0 = *(const short8*)&pgwF[(kb * 2 + 0) * 512 + l * 8];   // lane*16B
            short8 b1 = *(const short8*)&pgwF[(kb * 2 + 1) * 512 + l * 8];
            int aoff = (w + kh + 1) * 20 + (ln + kw + 1);
            int cg = (kb & 1) * 4 + quad;
            short8 af = *(const short8*)&patch[cg * PSTR + aoff * 8];
            o0 = __builtin_amdgcn_mfma_f32_16x16x32_f16(s2f(af), s2f(b0), o0, 0, 0, 0);
            o1 = __builtin_amdgcn_mfma_f32_16x16x32_f16(s2f(af), s2f(b1), o1, 0, 0, 0);
        }
#pragma unroll
        for (int tile = 0; tile < 2; ++tile) {
            int p = tile * 16 + ln;
            f32x4 a = tile ? o1 : o0;
            if (p < 27) {
                float bo = pg_b[p];
#pragma unroll
                for (int i = 0; i < 4; ++i) {
                    int wpx = w * 16 + quad * 4 + i;
                    float v = a[i] + bo;
                    if (p >= 18) v = 1.f / (1.f + expf(-v));
                    P_s[p * 129 + wpx] = v;
                }
            }
        }
    }
    __syncthreads();

    // ---- phase 2: sampling + main GEMM (M=128,N=64,K=576), B from wtF coalesced ----
    f32x4 acc[4];
#pragma unroll
    for (int nt = 0; nt < 4; ++nt) acc[nt] = (f32x4){0.f, 0.f, 0.f, 0.f};

    int qbase = quad * PSTR;             // per-thread constant plane base

    for (int kk = 0; kk < 9; ++kk) {
        // B fragments: coalesced lane*16B loads (L1/L2-hot)
        short8 bfr[2][4];
#pragma unroll
        for (int kb = 0; kb < 2; ++kb)
#pragma unroll
            for (int nt = 0; nt < 4; ++nt)
                bfr[kb][nt] = *(const short8*)&wtF[((kk * 2 + kb) * 4 + nt) * 512 + l * 8];

        // bilinear params from LDS (R12 body; stride 129)
        int ki = kk / 3, kj = kk - 3 * (kk / 3);
        float dyv = P_s[(2 * kk) * 129 + px];
        float dxv = P_s[(2 * kk + 1) * 129 + px];
        float m   = P_s[(18 + kk) * 129 + px];
        float ys = (float)(hh - 1 + ki) + dyv;
        float xs = (float)(ww - 1 + kj) + dxv;
        float y0f = floorf(ys), x0f = floorf(xs);
        int y0 = (int)y0f, x0 = (int)x0f;
        float ly = ys - y0f, lx = xs - x0f;
        float v0y = ((unsigned)y0 < 128u) ? 1.f : 0.f;
        float v1y = ((unsigned)(y0 + 1) < 128u) ? 1.f : 0.f;
        float v0x = ((unsigned)x0 < 128u) ? 1.f : 0.f;
        float v1x = ((unsigned)(x0 + 1) < 128u) ? 1.f : 0.f;
        float w00 = (1.f - ly) * (1.f - lx) * v0y * v0x * m;
        float w01 = (1.f - ly) * lx * v0y * v1x * m;
        float w10 = ly * (1.f - lx) * v1y * v0x * m;
        float w11 = ly * lx * v1y * v1x * m;
        int ly0 = y0 - base_y, lx0 = x0 - base_x;
        bool inp = ((unsigned)ly0 < 12u) && ((unsigned)lx0 < 18u);

        uint4 r[2][4];
        if (inp) {
            int pb = qbase + (ly0 * 20 + lx0) * 8;   // one base; corners = imm offsets
#pragma unroll
            for (int kb = 0; kb < 2; ++kb) {
                int base = pb + kb * 4 * PSTR;       // kb term folds to imm in ds_read
                r[kb][0] = *(const uint4*)&patch[base];
                r[kb][1] = *(const uint4*)&patch[base + 8];
                r[kb][2] = *(const uint4*)&patch[base + 160];
                r[kb][3] = *(const uint4*)&patch[base + 168];
            }
        } else {   // rare (|offset| >= 1): direct xh reads, clamped corners
            int y0c = min(max(y0, 0), 127), y1c = min(max(y0 + 1, 0), 127);
            int x0c = min(max(x0, 0), 127), x1c = min(max(x0 + 1, 0), 127);
            int base00 = (y0c * 128 + x0c) * 64;
            int dxo = (x1c - x0c) * 64, dyo = (y1c - y0c) * 8192;
#pragma unroll
            for (int kb = 0; kb < 2; ++kb) {
                int c0 = kb * 32 + quad * 8;
                r[kb][0] = *(const uint4*)&xbb[base00 + c0];
                r[kb][1] = *(const uint4*)&xbb[base00 + dxo + c0];
                r[kb][2] = *(const uint4*)&xbb[base00 + dyo + c0];
                r[kb][3] = *(const uint4*)&xbb[base00 + dyo + dxo + c0];
            }
        }

        // packed-f16 bilinear: 2 channels per step; pure v_pk_mul/fma_f16, no unpack/repack
        __half2 W00 = __float2half2_rn(w00), W01 = __float2half2_rn(w01);
        __half2 W10 = __float2half2_rn(w10), W11 = __float2half2_rn(w11);
        f16x8 af[2];
#pragma unroll
        for (int kb = 0; kb < 2; ++kb) {
            union { unsigned u[4]; f16x8 f; } afu;
#pragma unroll
            for (int p = 0; p < 4; ++p) {
                __half2 v = __hmul2(W00, u2h2(uget(r[kb][0], p)));
                v = __hfma2(W01, u2h2(uget(r[kb][1], p)), v);
                v = __hfma2(W10, u2h2(uget(r[kb][2], p)), v);
                v = __hfma2(W11, u2h2(uget(r[kb][3], p)), v);
                afu.u[p] = h22u(v);
            }
            af[kb] = afu.f;
        }

#pragma unroll
        for (int kb = 0; kb < 2; ++kb)
#pragma unroll
            for (int nt = 0; nt < 4; ++nt)
                acc[nt] = __builtin_amdgcn_mfma_f32_16x16x32_f16(af[kb], s2f(bfr[kb][nt]), acc[nt], 0, 0, 0);
    }

    // ---- epilogue: lane's 4 D-rows per nt = row w, cols quad*4..+3 -> float4 ----
    int ehh = h0 + w, eww = w0 + quad * 4;
#pragma unroll
    for (int nt = 0; nt < 4; ++nt) {
        int o = nt * 16 + ln;
        float bo = bias[o];
        float4 v;
        v.x = acc[nt][0] + bo; v.y = acc[nt][1] + bo;
        v.z = acc[nt][2] + bo; v.w = acc[nt][3] + bo;
        *(float4*)&out[((size_t)b * 64 + o) * 16384 + ehh * 128 + eww] = v;
    }
}

extern "C" void kernel_launch(void* const* d_in, const int* in_sizes, int n_in,
                              void* d_out, int out_size, void* d_ws, size_t ws_size,
                              hipStream_t stream) {
    const float* x      = (const float*)d_in[0];
    const float* weight = (const float*)d_in[1];
    const float* bias   = (const float*)d_in[2];
    const float* pg_w   = (const float*)d_in[3];
    const float* pg_b   = (const float*)d_in[4];
    float* out = (float*)d_out;

    unsigned short* xhB  = (unsigned short*)d_ws;        // 4*16384*64 f16 (8.39 MB)
    unsigned short* wtF  = xhB + (size_t)4 * 16384 * 64; // 36,864 f16 (fragment order)
    unsigned short* pgwF = wtF + 36864;                  // 18,432 f16 (fragment order)

    k_prep<<<2264, 256, 0, stream>>>(x, xhB, weight, pg_w, wtF, pgwF);
    k_fused<<<512, 512, 0, stream>>>(xhB, pgwF, pg_b, wtF, bias, out);
}